// Round 1
// baseline (3244.580 us; speedup 1.0000x reference)
//
#include <hip/hip_runtime.h>

// GCNLinkPredictor: 2-layer GCN, N=100000 nodes, E=3.2M edges, F=128, U=1000.
// out = concat( elu(gcn(elu(gcn(x,W1,b1)),W2,b2))[:U], x[U:] )
// gcn(x,W,b) = D^-1/2 (A+I) D^-1/2 (xW) + b,  deg = in-degree(dst) + 1.

#define F_DIM 128
#define U_USERS 1000

// ---------------- degree / normalization ----------------
__global__ void deg_count_kernel(const int* __restrict__ dst, float* __restrict__ deg, int E) {
    int e = blockIdx.x * blockDim.x + threadIdx.x;
    if (e < E) {
        int d = dst[e];
        if ((unsigned)d < 100000u * 2u)  // safety guard
            atomicAdd(&deg[d], 1.0f);
    }
}

__global__ void finalize_inv_kernel(float* __restrict__ deg, int n) {
    int i = blockIdx.x * blockDim.x + threadIdx.x;
    if (i < n) deg[i] = rsqrtf(deg[i] + 1.0f);
}

// ---------------- dense GEMM: out[n,128] = X[n,128] @ W[128,128] ----------------
// Block: 256 threads, covers 32 rows x 128 cols. W fully staged in LDS (64KB),
// X tile transposed in LDS (16KB, stride 32 -> broadcast reads, conflict-free
// inner loop). Each thread: 4 rows x 4 cols accumulator.
__global__ __launch_bounds__(256) void gemm_nn_kernel(const float* __restrict__ X,
                                                      const float* __restrict__ W,
                                                      float* __restrict__ out, int nrows) {
    __shared__ float Ws[F_DIM * F_DIM];   // 64 KB
    __shared__ float Xs[F_DIM * 32];      // transposed: Xs[k*32 + r], 16 KB

    int tid = threadIdx.x;
    // stage W: 16384 floats = 4096 float4 / 256 threads = 16 each
    const float4* W4 = (const float4*)W;
    float4* Ws4 = (float4*)Ws;
#pragma unroll
    for (int i = 0; i < 16; ++i) Ws4[tid + 256 * i] = W4[tid + 256 * i];

    int rowBase = blockIdx.x * 32;
    // stage X tile transposed: 32 rows x 128 cols = 1024 float4 / 256 threads = 4 each
#pragma unroll
    for (int i = 0; i < 4; ++i) {
        int j = tid + 256 * i;      // 0..1023
        int r = j >> 5;             // row in tile 0..31
        int k4 = j & 31;            // float4 index along k
        int row = rowBase + r;
        float4 v = make_float4(0.f, 0.f, 0.f, 0.f);
        if (row < nrows) v = ((const float4*)(X + (size_t)row * F_DIM))[k4];
        Xs[(4 * k4 + 0) * 32 + r] = v.x;
        Xs[(4 * k4 + 1) * 32 + r] = v.y;
        Xs[(4 * k4 + 2) * 32 + r] = v.z;
        Xs[(4 * k4 + 3) * 32 + r] = v.w;
    }
    __syncthreads();

    int c = tid & 31;               // col group: cols [4c, 4c+4)
    int r0 = (tid >> 5) * 4;        // rows [r0, r0+4) within tile
    float4 acc0 = make_float4(0, 0, 0, 0);
    float4 acc1 = make_float4(0, 0, 0, 0);
    float4 acc2 = make_float4(0, 0, 0, 0);
    float4 acc3 = make_float4(0, 0, 0, 0);

    for (int k = 0; k < F_DIM; ++k) {
        float4 wv = *(const float4*)(Ws + k * F_DIM + 4 * c);
        float x0 = Xs[k * 32 + r0 + 0];
        float x1 = Xs[k * 32 + r0 + 1];
        float x2 = Xs[k * 32 + r0 + 2];
        float x3 = Xs[k * 32 + r0 + 3];
        acc0.x += x0 * wv.x; acc0.y += x0 * wv.y; acc0.z += x0 * wv.z; acc0.w += x0 * wv.w;
        acc1.x += x1 * wv.x; acc1.y += x1 * wv.y; acc1.z += x1 * wv.z; acc1.w += x1 * wv.w;
        acc2.x += x2 * wv.x; acc2.y += x2 * wv.y; acc2.z += x2 * wv.z; acc2.w += x2 * wv.w;
        acc3.x += x3 * wv.x; acc3.y += x3 * wv.y; acc3.z += x3 * wv.z; acc3.w += x3 * wv.w;
    }

    float4 accs[4] = {acc0, acc1, acc2, acc3};
#pragma unroll
    for (int i = 0; i < 4; ++i) {
        int row = rowBase + r0 + i;
        if (row < nrows)
            ((float4*)(out + (size_t)row * F_DIM))[c] = accs[i];
    }
}

// ---------------- edge scatter: agg[dst] += xw[src] * coef ----------------
// One 64-lane wave per edge; each lane handles 2 features (float2 = 8B,
// 64 lanes = 512B coalesced row read). dstLimit filters layer-2 (dst < U).
__global__ __launch_bounds__(256) void scatter_edges_kernel(const float* __restrict__ xw,
                                                            const float* __restrict__ inv,
                                                            const int* __restrict__ src,
                                                            const int* __restrict__ dst,
                                                            float* __restrict__ agg,
                                                            int E, int nnodes, int dstLimit) {
    int eg = blockIdx.x * 4 + (threadIdx.x >> 6);
    int lane = threadIdx.x & 63;
    if (eg >= E) return;
    int d = dst[eg];
    if ((unsigned)d >= (unsigned)dstLimit) return;
    int s = src[eg];
    if ((unsigned)s >= (unsigned)nnodes) return;
    float coef = inv[s] * inv[d];
    float2 v = ((const float2*)(xw + (size_t)s * F_DIM))[lane];
    float* ap = agg + (size_t)d * F_DIM + lane * 2;
    atomicAdd(ap, v.x * coef);
    atomicAdd(ap + 1, v.y * coef);
}

// ---------------- epilogue: out = elu(agg + xw*inv^2 + b) ----------------
__global__ void post_elu_kernel(const float* __restrict__ xw, const float* __restrict__ inv,
                                const float* __restrict__ b, float* __restrict__ agg,
                                int nrows) {
    int i = blockIdx.x * blockDim.x + threadIdx.x;
    int total = nrows * F_DIM;
    if (i >= total) return;
    int nidx = i >> 7;
    int f = i & 127;
    float iv = inv[nidx];
    float v = agg[i] + xw[i] * iv * iv + b[f];
    agg[i] = v > 0.f ? v : expf(v) - 1.f;
}

extern "C" void kernel_launch(void* const* d_in, const int* in_sizes, int n_in,
                              void* d_out, int out_size, void* d_ws, size_t ws_size,
                              hipStream_t stream) {
    const float* x  = (const float*)d_in[0];
    const int*   ei = (const int*)d_in[1];   // [2, E] int32
    const float* W1 = (const float*)d_in[2];
    const float* b1 = (const float*)d_in[3];
    const float* W2 = (const float*)d_in[4];
    const float* b2 = (const float*)d_in[5];
    float* out = (float*)d_out;

    int n = in_sizes[0] / F_DIM;   // 100000
    int E = in_sizes[1] / 2;       // 3200000
    const int* srcI = ei;
    const int* dstI = ei + E;

    // workspace layout
    float* xw  = (float*)d_ws;                       // n*128 floats (xw1, then xw2)
    float* agg = xw + (size_t)n * F_DIM;             // n*128 floats (agg1 -> h1)
    float* inv = agg + (size_t)n * F_DIM;            // n floats (deg -> inv_sqrt)

    // degree + normalization
    hipMemsetAsync(inv, 0, (size_t)n * sizeof(float), stream);
    hipMemsetAsync(agg, 0, (size_t)n * F_DIM * sizeof(float), stream);
    deg_count_kernel<<<(E + 255) / 256, 256, 0, stream>>>(dstI, inv, E);
    finalize_inv_kernel<<<(n + 255) / 256, 256, 0, stream>>>(inv, n);

    // ---- layer 1 (full graph) ----
    gemm_nn_kernel<<<(n + 31) / 32, 256, 0, stream>>>(x, W1, xw, n);
    scatter_edges_kernel<<<(E + 3) / 4, 256, 0, stream>>>(xw, inv, srcI, dstI, agg, E, n, n);
    post_elu_kernel<<<((n * F_DIM) + 255) / 256, 256, 0, stream>>>(xw, inv, b1, agg, n);
    // agg now holds h1

    // ---- layer 2 (only dst < U rows of output matter) ----
    gemm_nn_kernel<<<(n + 31) / 32, 256, 0, stream>>>(agg, W2, xw, n);   // xw = h1 @ W2
    hipMemsetAsync(out, 0, (size_t)U_USERS * F_DIM * sizeof(float), stream);
    scatter_edges_kernel<<<(E + 3) / 4, 256, 0, stream>>>(xw, inv, srcI, dstI, out, E, n, U_USERS);
    post_elu_kernel<<<((U_USERS * F_DIM) + 255) / 256, 256, 0, stream>>>(xw, inv, b2, out, U_USERS);

    // ---- passthrough rows [U:] = x[U:] ----
    hipMemcpyAsync(out + (size_t)U_USERS * F_DIM, x + (size_t)U_USERS * F_DIM,
                   (size_t)(n - U_USERS) * F_DIM * sizeof(float),
                   hipMemcpyDeviceToDevice, stream);
}

// Round 2
// 843.864 us; speedup vs baseline: 3.8449x; 3.8449x over previous
//
#include <hip/hip_runtime.h>

// GCNLinkPredictor: 2-layer GCN, N=100000, E=3.2M, F=128, U=1000.
// R2: replace atomic scatter with on-device CSR (bucket by dst) + pull-gather
// with fused epilogue (norm + self-loop + bias + ELU). xw (51MB) fits in the
// 256MB Infinity Cache, so edge gathers are LLC hits instead of atomic RMW
// round-trips to HBM.

#define F_DIM 128
#define U_USERS 1000
#define SCAN_CHUNK 1024

// ---------------- degree histogram (int) ----------------
__global__ void deg_count_kernel(const int* __restrict__ dst, int* __restrict__ degI, int E, int n) {
    int e = blockIdx.x * blockDim.x + threadIdx.x;
    if (e < E) {
        int d = dst[e];
        if ((unsigned)d < (unsigned)n) atomicAdd(&degI[d], 1);
    }
}

__global__ void finalize_inv_kernel(const int* __restrict__ degI, float* __restrict__ inv, int n) {
    int i = blockIdx.x * blockDim.x + threadIdx.x;
    if (i < n) inv[i] = rsqrtf((float)degI[i] + 1.0f);
}

// ---------------- exclusive scan (3-kernel, 1024 elems/block) ----------------
__global__ void scan_reduce_kernel(const int* __restrict__ degI, int* __restrict__ partial, int n) {
    __shared__ int sdata[256];
    int b = blockIdx.x, t = threadIdx.x;
    int base = b * SCAN_CHUNK;
    int sum = 0;
#pragma unroll
    for (int i = 0; i < 4; ++i) {
        int idx = base + t + 256 * i;
        if (idx < n) sum += degI[idx];
    }
    sdata[t] = sum; __syncthreads();
    for (int s = 128; s > 0; s >>= 1) {
        if (t < s) sdata[t] += sdata[t + s];
        __syncthreads();
    }
    if (t == 0) partial[b] = sdata[0];
}

__global__ void scan_partials_kernel(int* __restrict__ partial, int nb) {
    if (threadIdx.x == 0 && blockIdx.x == 0) {
        int run = 0;
        for (int i = 0; i < nb; ++i) { int v = partial[i]; partial[i] = run; run += v; }
    }
}

__global__ void scan_final_kernel(const int* __restrict__ degI, const int* __restrict__ partial,
                                  int* __restrict__ rp, int n) {
    __shared__ int sthread[256];
    int b = blockIdx.x, t = threadIdx.x;
    int base = b * SCAN_CHUNK;
    int v[4]; int sum = 0;
#pragma unroll
    for (int i = 0; i < 4; ++i) {
        int idx = base + 4 * t + i;            // thread owns contiguous 4
        v[i] = (idx < n) ? degI[idx] : 0;
        sum += v[i];
    }
    sthread[t] = sum; __syncthreads();
    // Hillis-Steele inclusive scan over thread sums
    for (int ofs = 1; ofs < 256; ofs <<= 1) {
        int val = (t >= ofs) ? sthread[t - ofs] : 0;
        __syncthreads();
        sthread[t] += val;
        __syncthreads();
    }
    int run = sthread[t] - sum + partial[b];   // exclusive prefix for this thread
#pragma unroll
    for (int i = 0; i < 4; ++i) {
        int idx = base + 4 * t + i;
        if (idx < n) rp[idx] = run;
        run += v[i];
    }
}

// ---------------- CSR fill: bump rp[d] (rp becomes shifted: rp[d]=bucket end) ----
__global__ void fill_csr_kernel(const int* __restrict__ src, const int* __restrict__ dst,
                                int* __restrict__ rp, int* __restrict__ col, int E, int n) {
    int e = blockIdx.x * blockDim.x + threadIdx.x;
    if (e < E) {
        int d = dst[e], s = src[e];
        if ((unsigned)d < (unsigned)n && (unsigned)s < (unsigned)n) {
            int pos = atomicAdd(&rp[d], 1);
            col[pos] = s;
        }
    }
}

// ---------------- dense GEMM: out[n,128] = X[n,128] @ W[128,128] ----------------
__global__ __launch_bounds__(256) void gemm_nn_kernel(const float* __restrict__ X,
                                                      const float* __restrict__ W,
                                                      float* __restrict__ out, int nrows) {
    __shared__ float Ws[F_DIM * F_DIM];   // 64 KB
    __shared__ float Xs[F_DIM * 32];      // transposed, 16 KB

    int tid = threadIdx.x;
    const float4* W4 = (const float4*)W;
    float4* Ws4 = (float4*)Ws;
#pragma unroll
    for (int i = 0; i < 16; ++i) Ws4[tid + 256 * i] = W4[tid + 256 * i];

    int rowBase = blockIdx.x * 32;
#pragma unroll
    for (int i = 0; i < 4; ++i) {
        int j = tid + 256 * i;
        int r = j >> 5;
        int k4 = j & 31;
        int row = rowBase + r;
        float4 v = make_float4(0.f, 0.f, 0.f, 0.f);
        if (row < nrows) v = ((const float4*)(X + (size_t)row * F_DIM))[k4];
        Xs[(4 * k4 + 0) * 32 + r] = v.x;
        Xs[(4 * k4 + 1) * 32 + r] = v.y;
        Xs[(4 * k4 + 2) * 32 + r] = v.z;
        Xs[(4 * k4 + 3) * 32 + r] = v.w;
    }
    __syncthreads();

    int c = tid & 31;
    int r0 = (tid >> 5) * 4;
    float4 acc0 = make_float4(0, 0, 0, 0);
    float4 acc1 = make_float4(0, 0, 0, 0);
    float4 acc2 = make_float4(0, 0, 0, 0);
    float4 acc3 = make_float4(0, 0, 0, 0);

    for (int k = 0; k < F_DIM; ++k) {
        float4 wv = *(const float4*)(Ws + k * F_DIM + 4 * c);
        float x0 = Xs[k * 32 + r0 + 0];
        float x1 = Xs[k * 32 + r0 + 1];
        float x2 = Xs[k * 32 + r0 + 2];
        float x3 = Xs[k * 32 + r0 + 3];
        acc0.x += x0 * wv.x; acc0.y += x0 * wv.y; acc0.z += x0 * wv.z; acc0.w += x0 * wv.w;
        acc1.x += x1 * wv.x; acc1.y += x1 * wv.y; acc1.z += x1 * wv.z; acc1.w += x1 * wv.w;
        acc2.x += x2 * wv.x; acc2.y += x2 * wv.y; acc2.z += x2 * wv.z; acc2.w += x2 * wv.w;
        acc3.x += x3 * wv.x; acc3.y += x3 * wv.y; acc3.z += x3 * wv.z; acc3.w += x3 * wv.w;
    }

    float4 accs[4] = {acc0, acc1, acc2, acc3};
#pragma unroll
    for (int i = 0; i < 4; ++i) {
        int row = rowBase + r0 + i;
        if (row < nrows)
            ((float4*)(out + (size_t)row * F_DIM))[c] = accs[i];
    }
}

// ---------------- pull-gather + fused epilogue ----------------
// One wave per dst node; lane owns 2 features (float2). acc = sum inv[s]*xw[s];
// out = elu(acc*inv[d] + xw[d]*inv[d]^2 + b).  rp is the SHIFTED rowptr
// (rp[d] = bucket end; start = d ? rp[d-1] : 0).
__global__ __launch_bounds__(256) void gather_nodes_kernel(const float* __restrict__ xw,
                                                           const float* __restrict__ inv,
                                                           const int* __restrict__ rp,
                                                           const int* __restrict__ col,
                                                           const float* __restrict__ b,
                                                           float* __restrict__ outbuf,
                                                           int nnodes) {
    int node = blockIdx.x * 4 + (threadIdx.x >> 6);
    int lane = threadIdx.x & 63;
    if (node >= nnodes) return;
    int start = (node == 0) ? 0 : rp[node - 1];
    int end = rp[node];

    float accx = 0.f, accy = 0.f;
    for (int base = start; base < end; base += 64) {
        int j = base + lane;
        int s_l = 0; float c_l = 0.f;
        if (j < end) { s_l = col[j]; c_l = inv[s_l]; }
        int cnt = min(64, end - base);
        int i = 0;
        for (; i + 4 <= cnt; i += 4) {          // 4 independent gathers in flight
            int s0 = __shfl(s_l, i + 0); float f0 = __shfl(c_l, i + 0);
            int s1 = __shfl(s_l, i + 1); float f1 = __shfl(c_l, i + 1);
            int s2 = __shfl(s_l, i + 2); float f2 = __shfl(c_l, i + 2);
            int s3 = __shfl(s_l, i + 3); float f3 = __shfl(c_l, i + 3);
            float2 v0 = ((const float2*)(xw + (size_t)s0 * F_DIM))[lane];
            float2 v1 = ((const float2*)(xw + (size_t)s1 * F_DIM))[lane];
            float2 v2 = ((const float2*)(xw + (size_t)s2 * F_DIM))[lane];
            float2 v3 = ((const float2*)(xw + (size_t)s3 * F_DIM))[lane];
            accx += v0.x * f0 + v1.x * f1 + v2.x * f2 + v3.x * f3;
            accy += v0.y * f0 + v1.y * f1 + v2.y * f2 + v3.y * f3;
        }
        for (; i < cnt; ++i) {
            int s0 = __shfl(s_l, i); float f0 = __shfl(c_l, i);
            float2 v0 = ((const float2*)(xw + (size_t)s0 * F_DIM))[lane];
            accx += v0.x * f0;
            accy += v0.y * f0;
        }
    }

    float ivd = inv[node];
    float2 self = ((const float2*)(xw + (size_t)node * F_DIM))[lane];
    float vx = accx * ivd + self.x * ivd * ivd + b[lane * 2];
    float vy = accy * ivd + self.y * ivd * ivd + b[lane * 2 + 1];
    vx = vx > 0.f ? vx : expf(vx) - 1.f;
    vy = vy > 0.f ? vy : expf(vy) - 1.f;
    ((float2*)(outbuf + (size_t)node * F_DIM))[lane] = make_float2(vx, vy);
}

extern "C" void kernel_launch(void* const* d_in, const int* in_sizes, int n_in,
                              void* d_out, int out_size, void* d_ws, size_t ws_size,
                              hipStream_t stream) {
    const float* x  = (const float*)d_in[0];
    const int*   ei = (const int*)d_in[1];   // [2, E] int32
    const float* W1 = (const float*)d_in[2];
    const float* b1 = (const float*)d_in[3];
    const float* W2 = (const float*)d_in[4];
    const float* b2 = (const float*)d_in[5];
    float* out = (float*)d_out;

    int n = in_sizes[0] / F_DIM;   // 100000
    int E = in_sizes[1] / 2;       // 3200000
    const int* srcI = ei;
    const int* dstI = ei + E;

    // workspace layout (~116.5 MB)
    float* xw   = (float*)d_ws;                        // n*128 floats
    float* h1   = xw + (size_t)n * F_DIM;              // n*128 floats
    float* inv  = h1 + (size_t)n * F_DIM;              // n floats
    int* degI   = (int*)(inv + n);                     // n ints
    int* rp     = degI + n;                            // n ints (becomes shifted rowptr)
    int* partial= rp + n;                              // 1024 ints
    int* col    = partial + 1024;                      // E ints

    int nb = (n + SCAN_CHUNK - 1) / SCAN_CHUNK;        // 98

    // ---- CSR build ----
    hipMemsetAsync(degI, 0, (size_t)n * sizeof(int), stream);
    deg_count_kernel<<<(E + 255) / 256, 256, 0, stream>>>(dstI, degI, E, n);
    finalize_inv_kernel<<<(n + 255) / 256, 256, 0, stream>>>(degI, inv, n);
    scan_reduce_kernel<<<nb, 256, 0, stream>>>(degI, partial, n);
    scan_partials_kernel<<<1, 64, 0, stream>>>(partial, nb);
    scan_final_kernel<<<nb, 256, 0, stream>>>(degI, partial, rp, n);
    fill_csr_kernel<<<(E + 255) / 256, 256, 0, stream>>>(srcI, dstI, rp, col, E, n);

    // ---- layer 1 ----
    gemm_nn_kernel<<<(n + 31) / 32, 256, 0, stream>>>(x, W1, xw, n);
    gather_nodes_kernel<<<(n + 3) / 4, 256, 0, stream>>>(xw, inv, rp, col, b1, h1, n);

    // ---- layer 2 (only first U output rows needed) ----
    gemm_nn_kernel<<<(n + 31) / 32, 256, 0, stream>>>(h1, W2, xw, n);   // xw = h1 @ W2
    gather_nodes_kernel<<<(U_USERS + 3) / 4, 256, 0, stream>>>(xw, inv, rp, col, b2, out, U_USERS);

    // ---- passthrough rows [U:] = x[U:] ----
    hipMemcpyAsync(out + (size_t)U_USERS * F_DIM, x + (size_t)U_USERS * F_DIM,
                   (size_t)(n - U_USERS) * F_DIM * sizeof(float),
                   hipMemcpyDeviceToDevice, stream);
}

// Round 3
// 518.408 us; speedup vs baseline: 6.2587x; 1.6278x over previous
//
#include <hip/hip_runtime.h>

// GCNLinkPredictor: 2-layer GCN, N=100000, E=3.2M, F=128, U=1000.
// R3: output-dependency frontier. Only h2[:U] survives -> only frontier nodes
// (srcs of edges into [0,U) plus [0,U) itself, ~33K) need h1 / layer-2 GEMM,
// and only edges with dst in frontier (~1.07M of 3.2M) need CSR + gather.
// CSR col region shrinks 12.8MB -> ~4.3MB (fits L2 -> write amp collapses).

#define F_DIM 128
#define U_USERS 1000
#define SCAN_CHUNK 1024
#define NFCAP 48000   // frontier cap (expected ~33K; binomial tail << cap)

// ---- pass 1: full in-degree histogram + frontier marking ----
__global__ void deg_mark_kernel(const int* __restrict__ src, const int* __restrict__ dst,
                                int* __restrict__ degI, int* __restrict__ fr, int E, int n) {
    int e = blockIdx.x * blockDim.x + threadIdx.x;
    if (e < E) {
        int d = dst[e];
        if ((unsigned)d < (unsigned)n) {
            atomicAdd(&degI[d], 1);
            if (d < U_USERS) {
                int s = src[e];
                if ((unsigned)s < (unsigned)n) fr[s] = 1;   // idempotent store
            }
        }
    }
}

// ---- prep: fr for [0,U), inv = rsqrt(deg+1), degF = fr ? deg : 0 ----
__global__ void prep_kernel(const int* __restrict__ degI, int* __restrict__ fr,
                            int* __restrict__ degF, float* __restrict__ inv, int n) {
    int i = blockIdx.x * blockDim.x + threadIdx.x;
    if (i >= n) return;
    if (i < U_USERS) fr[i] = 1;
    inv[i] = rsqrtf((float)degI[i] + 1.0f);
    degF[i] = fr[i] ? degI[i] : 0;
}

// ---- generic exclusive scan (3 kernels, 1024/block) ----
__global__ void scan_reduce_kernel(const int* __restrict__ in, int* __restrict__ partial, int n) {
    __shared__ int sdata[256];
    int b = blockIdx.x, t = threadIdx.x;
    int base = b * SCAN_CHUNK;
    int sum = 0;
#pragma unroll
    for (int i = 0; i < 4; ++i) {
        int idx = base + t + 256 * i;
        if (idx < n) sum += in[idx];
    }
    sdata[t] = sum; __syncthreads();
    for (int s = 128; s > 0; s >>= 1) {
        if (t < s) sdata[t] += sdata[t + s];
        __syncthreads();
    }
    if (t == 0) partial[b] = sdata[0];
}

__global__ void scan_partials_kernel(int* __restrict__ partial, int nb) {
    if (threadIdx.x == 0 && blockIdx.x == 0) {
        int run = 0;
        for (int i = 0; i < nb; ++i) { int v = partial[i]; partial[i] = run; run += v; }
    }
}

__global__ void scan_final_kernel(const int* __restrict__ in, const int* __restrict__ partial,
                                  int* __restrict__ outsc, int n) {
    __shared__ int sthread[256];
    int b = blockIdx.x, t = threadIdx.x;
    int base = b * SCAN_CHUNK;
    int v[4]; int sum = 0;
#pragma unroll
    for (int i = 0; i < 4; ++i) {
        int idx = base + 4 * t + i;
        v[i] = (idx < n) ? in[idx] : 0;
        sum += v[i];
    }
    sthread[t] = sum; __syncthreads();
    for (int ofs = 1; ofs < 256; ofs <<= 1) {
        int val = (t >= ofs) ? sthread[t - ofs] : 0;
        __syncthreads();
        sthread[t] += val;
        __syncthreads();
    }
    int run = sthread[t] - sum + partial[b];
#pragma unroll
    for (int i = 0; i < 4; ++i) {
        int idx = base + 4 * t + i;
        if (idx < n) outsc[idx] = run;
        run += v[i];
    }
}

// ---- frontier list + count ----
__global__ void flist_kernel(const int* __restrict__ fr, const int* __restrict__ remap,
                             int* __restrict__ flist, int* __restrict__ nf_dev, int n) {
    int i = blockIdx.x * blockDim.x + threadIdx.x;
    if (i >= n) return;
    if (fr[i]) {
        int ci = remap[i];
        if (ci < NFCAP) flist[ci] = i;
    }
    if (i == n - 1) *nf_dev = min(remap[i] + fr[i], NFCAP);
}

// ---- CSR fill (frontier rows only); rp becomes shifted rowptr (bucket end) ----
__global__ void fill_csr_kernel(const int* __restrict__ src, const int* __restrict__ dst,
                                const int* __restrict__ fr,
                                int* __restrict__ rp, int* __restrict__ col, int E, int n) {
    int e = blockIdx.x * blockDim.x + threadIdx.x;
    if (e < E) {
        int d = dst[e], s = src[e];
        if ((unsigned)d < (unsigned)n && (unsigned)s < (unsigned)n && fr[d]) {
            int pos = atomicAdd(&rp[d], 1);
            if ((unsigned)pos < (unsigned)E) col[pos] = s;
        }
    }
}

// ---- dense GEMM: out[n,128] = X[n,128] @ W[128,128] (static row count) ----
__global__ __launch_bounds__(256) void gemm_nn_kernel(const float* __restrict__ X,
                                                      const float* __restrict__ W,
                                                      float* __restrict__ out, int nrows) {
    __shared__ float Ws[F_DIM * F_DIM];
    __shared__ float Xs[F_DIM * 32];

    int tid = threadIdx.x;
    const float4* W4 = (const float4*)W;
    float4* Ws4 = (float4*)Ws;
#pragma unroll
    for (int i = 0; i < 16; ++i) Ws4[tid + 256 * i] = W4[tid + 256 * i];

    int rowBase = blockIdx.x * 32;
#pragma unroll
    for (int i = 0; i < 4; ++i) {
        int j = tid + 256 * i;
        int r = j >> 5;
        int k4 = j & 31;
        int row = rowBase + r;
        float4 v = make_float4(0.f, 0.f, 0.f, 0.f);
        if (row < nrows) v = ((const float4*)(X + (size_t)row * F_DIM))[k4];
        Xs[(4 * k4 + 0) * 32 + r] = v.x;
        Xs[(4 * k4 + 1) * 32 + r] = v.y;
        Xs[(4 * k4 + 2) * 32 + r] = v.z;
        Xs[(4 * k4 + 3) * 32 + r] = v.w;
    }
    __syncthreads();

    int c = tid & 31;
    int r0 = (tid >> 5) * 4;
    float4 acc0 = make_float4(0, 0, 0, 0);
    float4 acc1 = make_float4(0, 0, 0, 0);
    float4 acc2 = make_float4(0, 0, 0, 0);
    float4 acc3 = make_float4(0, 0, 0, 0);

    for (int k = 0; k < F_DIM; ++k) {
        float4 wv = *(const float4*)(Ws + k * F_DIM + 4 * c);
        float x0 = Xs[k * 32 + r0 + 0];
        float x1 = Xs[k * 32 + r0 + 1];
        float x2 = Xs[k * 32 + r0 + 2];
        float x3 = Xs[k * 32 + r0 + 3];
        acc0.x += x0 * wv.x; acc0.y += x0 * wv.y; acc0.z += x0 * wv.z; acc0.w += x0 * wv.w;
        acc1.x += x1 * wv.x; acc1.y += x1 * wv.y; acc1.z += x1 * wv.z; acc1.w += x1 * wv.w;
        acc2.x += x2 * wv.x; acc2.y += x2 * wv.y; acc2.z += x2 * wv.z; acc2.w += x2 * wv.w;
        acc3.x += x3 * wv.x; acc3.y += x3 * wv.y; acc3.z += x3 * wv.z; acc3.w += x3 * wv.w;
    }

    float4 accs[4] = {acc0, acc1, acc2, acc3};
#pragma unroll
    for (int i = 0; i < 4; ++i) {
        int row = rowBase + r0 + i;
        if (row < nrows)
            ((float4*)(out + (size_t)row * F_DIM))[c] = accs[i];
    }
}

// ---- GEMM with device-side row count (compact frontier rows) ----
__global__ __launch_bounds__(256) void gemm_nn_dyn_kernel(const float* __restrict__ X,
                                                          const float* __restrict__ W,
                                                          float* __restrict__ out,
                                                          const int* __restrict__ nrows_p) {
    int nrows = *nrows_p;
    int rowBase = blockIdx.x * 32;
    if (rowBase >= nrows) return;

    __shared__ float Ws[F_DIM * F_DIM];
    __shared__ float Xs[F_DIM * 32];

    int tid = threadIdx.x;
    const float4* W4 = (const float4*)W;
    float4* Ws4 = (float4*)Ws;
#pragma unroll
    for (int i = 0; i < 16; ++i) Ws4[tid + 256 * i] = W4[tid + 256 * i];

#pragma unroll
    for (int i = 0; i < 4; ++i) {
        int j = tid + 256 * i;
        int r = j >> 5;
        int k4 = j & 31;
        int row = rowBase + r;
        float4 v = make_float4(0.f, 0.f, 0.f, 0.f);
        if (row < nrows) v = ((const float4*)(X + (size_t)row * F_DIM))[k4];
        Xs[(4 * k4 + 0) * 32 + r] = v.x;
        Xs[(4 * k4 + 1) * 32 + r] = v.y;
        Xs[(4 * k4 + 2) * 32 + r] = v.z;
        Xs[(4 * k4 + 3) * 32 + r] = v.w;
    }
    __syncthreads();

    int c = tid & 31;
    int r0 = (tid >> 5) * 4;
    float4 acc0 = make_float4(0, 0, 0, 0);
    float4 acc1 = make_float4(0, 0, 0, 0);
    float4 acc2 = make_float4(0, 0, 0, 0);
    float4 acc3 = make_float4(0, 0, 0, 0);

    for (int k = 0; k < F_DIM; ++k) {
        float4 wv = *(const float4*)(Ws + k * F_DIM + 4 * c);
        float x0 = Xs[k * 32 + r0 + 0];
        float x1 = Xs[k * 32 + r0 + 1];
        float x2 = Xs[k * 32 + r0 + 2];
        float x3 = Xs[k * 32 + r0 + 3];
        acc0.x += x0 * wv.x; acc0.y += x0 * wv.y; acc0.z += x0 * wv.z; acc0.w += x0 * wv.w;
        acc1.x += x1 * wv.x; acc1.y += x1 * wv.y; acc1.z += x1 * wv.z; acc1.w += x1 * wv.w;
        acc2.x += x2 * wv.x; acc2.y += x2 * wv.y; acc2.z += x2 * wv.z; acc2.w += x2 * wv.w;
        acc3.x += x3 * wv.x; acc3.y += x3 * wv.y; acc3.z += x3 * wv.z; acc3.w += x3 * wv.w;
    }

    float4 accs[4] = {acc0, acc1, acc2, acc3};
#pragma unroll
    for (int i = 0; i < 4; ++i) {
        int row = rowBase + r0 + i;
        if (row < nrows)
            ((float4*)(out + (size_t)row * F_DIM))[c] = accs[i];
    }
}

// ---- layer-1 gather over compact frontier rows ----
// h1c[ci] = elu( (sum_s inv[s]*xw[s]) * inv[node] + xw[node]*inv[node]^2 + b )
__global__ __launch_bounds__(256) void gather_l1_kernel(const float* __restrict__ xw,
                                                        const float* __restrict__ inv,
                                                        const int* __restrict__ rp,
                                                        const int* __restrict__ col,
                                                        const int* __restrict__ flist,
                                                        const int* __restrict__ nf_p,
                                                        const float* __restrict__ b,
                                                        float* __restrict__ h1c) {
    int ci = blockIdx.x * 4 + (threadIdx.x >> 6);
    if (ci >= *nf_p) return;
    int lane = threadIdx.x & 63;
    int node = flist[ci];
    int start = (node == 0) ? 0 : rp[node - 1];
    int end = rp[node];

    float accx = 0.f, accy = 0.f;
    for (int base = start; base < end; base += 64) {
        int j = base + lane;
        int s_l = 0; float c_l = 0.f;
        if (j < end) { s_l = col[j]; c_l = inv[s_l]; }
        int cnt = min(64, end - base);
        int i = 0;
        for (; i + 4 <= cnt; i += 4) {
            int s0 = __shfl(s_l, i + 0); float f0 = __shfl(c_l, i + 0);
            int s1 = __shfl(s_l, i + 1); float f1 = __shfl(c_l, i + 1);
            int s2 = __shfl(s_l, i + 2); float f2 = __shfl(c_l, i + 2);
            int s3 = __shfl(s_l, i + 3); float f3 = __shfl(c_l, i + 3);
            float2 v0 = ((const float2*)(xw + (size_t)s0 * F_DIM))[lane];
            float2 v1 = ((const float2*)(xw + (size_t)s1 * F_DIM))[lane];
            float2 v2 = ((const float2*)(xw + (size_t)s2 * F_DIM))[lane];
            float2 v3 = ((const float2*)(xw + (size_t)s3 * F_DIM))[lane];
            accx += v0.x * f0 + v1.x * f1 + v2.x * f2 + v3.x * f3;
            accy += v0.y * f0 + v1.y * f1 + v2.y * f2 + v3.y * f3;
        }
        for (; i < cnt; ++i) {
            int s0 = __shfl(s_l, i); float f0 = __shfl(c_l, i);
            float2 v0 = ((const float2*)(xw + (size_t)s0 * F_DIM))[lane];
            accx += v0.x * f0;
            accy += v0.y * f0;
        }
    }

    float ivd = inv[node];
    float2 self = ((const float2*)(xw + (size_t)node * F_DIM))[lane];
    float vx = accx * ivd + self.x * ivd * ivd + b[lane * 2];
    float vy = accy * ivd + self.y * ivd * ivd + b[lane * 2 + 1];
    vx = vx > 0.f ? vx : expf(vx) - 1.f;
    vy = vy > 0.f ? vy : expf(vy) - 1.f;
    ((float2*)(h1c + (size_t)ci * F_DIM))[lane] = make_float2(vx, vy);
}

// ---- layer-2 gather over rows [0,U): cols remapped into compact xwc ----
__global__ __launch_bounds__(256) void gather_l2_kernel(const float* __restrict__ xwc,
                                                        const float* __restrict__ inv,
                                                        const int* __restrict__ rp,
                                                        const int* __restrict__ col,
                                                        const int* __restrict__ remap,
                                                        const float* __restrict__ b,
                                                        float* __restrict__ out) {
    int node = blockIdx.x * 4 + (threadIdx.x >> 6);   // node < U, compact idx == node
    if (node >= U_USERS) return;
    int lane = threadIdx.x & 63;
    int start = (node == 0) ? 0 : rp[node - 1];
    int end = rp[node];

    float accx = 0.f, accy = 0.f;
    for (int base = start; base < end; base += 64) {
        int j = base + lane;
        int r_l = 0; float c_l = 0.f;
        if (j < end) { int s = col[j]; c_l = inv[s]; r_l = remap[s]; }
        int cnt = min(64, end - base);
        for (int i = 0; i < cnt; ++i) {
            int r0 = __shfl(r_l, i); float f0 = __shfl(c_l, i);
            float2 v0 = ((const float2*)(xwc + (size_t)r0 * F_DIM))[lane];
            accx += v0.x * f0;
            accy += v0.y * f0;
        }
    }

    float ivd = inv[node];
    float2 self = ((const float2*)(xwc + (size_t)node * F_DIM))[lane];  // remap[node]==node for node<U
    float vx = accx * ivd + self.x * ivd * ivd + b[lane * 2];
    float vy = accy * ivd + self.y * ivd * ivd + b[lane * 2 + 1];
    vx = vx > 0.f ? vx : expf(vx) - 1.f;
    vy = vy > 0.f ? vy : expf(vy) - 1.f;
    ((float2*)(out + (size_t)node * F_DIM))[lane] = make_float2(vx, vy);
}

extern "C" void kernel_launch(void* const* d_in, const int* in_sizes, int n_in,
                              void* d_out, int out_size, void* d_ws, size_t ws_size,
                              hipStream_t stream) {
    const float* x  = (const float*)d_in[0];
    const int*   ei = (const int*)d_in[1];   // [2, E] int32
    const float* W1 = (const float*)d_in[2];
    const float* b1 = (const float*)d_in[3];
    const float* W2 = (const float*)d_in[4];
    const float* b2 = (const float*)d_in[5];
    float* out = (float*)d_out;

    int n = in_sizes[0] / F_DIM;   // 100000
    int E = in_sizes[1] / 2;       // 3200000
    const int* srcI = ei;
    const int* dstI = ei + E;

    // workspace layout (~92 MB)
    float* xw    = (float*)d_ws;                  // n*128 f (xw1; reused as xwc for layer 2)
    float* h1c   = xw + (size_t)n * F_DIM;        // NFCAP*128 f
    float* inv   = h1c + (size_t)NFCAP * F_DIM;   // n f
    int* degI    = (int*)(inv + n);               // n
    int* fr      = degI + n;                      // n
    int* degF    = fr + n;                        // n
    int* remap   = degF + n;                      // n
    int* rp      = remap + n;                     // n
    int* flist   = rp + n;                        // NFCAP
    int* partialA= flist + NFCAP;                 // 1024
    int* partialB= partialA + 1024;               // 1024
    int* nf_dev  = partialB + 1024;               // 1 (+pad)
    int* col     = nf_dev + 16;                   // E

    int nb = (n + SCAN_CHUNK - 1) / SCAN_CHUNK;   // 98

    hipMemsetAsync(degI, 0, (size_t)n * sizeof(int), stream);
    hipMemsetAsync(fr, 0, (size_t)n * sizeof(int), stream);

    // frontier + degrees + CSR
    deg_mark_kernel<<<(E + 255) / 256, 256, 0, stream>>>(srcI, dstI, degI, fr, E, n);
    prep_kernel<<<(n + 255) / 256, 256, 0, stream>>>(degI, fr, degF, inv, n);
    scan_reduce_kernel<<<nb, 256, 0, stream>>>(degF, partialA, n);
    scan_partials_kernel<<<1, 64, 0, stream>>>(partialA, nb);
    scan_final_kernel<<<nb, 256, 0, stream>>>(degF, partialA, rp, n);
    scan_reduce_kernel<<<nb, 256, 0, stream>>>(fr, partialB, n);
    scan_partials_kernel<<<1, 64, 0, stream>>>(partialB, nb);
    scan_final_kernel<<<nb, 256, 0, stream>>>(fr, partialB, remap, n);
    flist_kernel<<<(n + 255) / 256, 256, 0, stream>>>(fr, remap, flist, nf_dev, n);
    fill_csr_kernel<<<(E + 255) / 256, 256, 0, stream>>>(srcI, dstI, fr, rp, col, E, n);

    // layer 1: full GEMM, frontier-only gather
    gemm_nn_kernel<<<(n + 31) / 32, 256, 0, stream>>>(x, W1, xw, n);
    gather_l1_kernel<<<(NFCAP + 3) / 4, 256, 0, stream>>>(xw, inv, rp, col, flist, nf_dev, b1, h1c);

    // layer 2: compact GEMM (nf rows), gather over U rows
    gemm_nn_dyn_kernel<<<(NFCAP + 31) / 32, 256, 0, stream>>>(h1c, W2, xw, nf_dev);  // xw = xwc
    gather_l2_kernel<<<(U_USERS + 3) / 4, 256, 0, stream>>>(xw, inv, rp, col, remap, b2, out);

    // passthrough rows [U:]
    hipMemcpyAsync(out + (size_t)U_USERS * F_DIM, x + (size_t)U_USERS * F_DIM,
                   (size_t)(n - U_USERS) * F_DIM * sizeof(float),
                   hipMemcpyDeviceToDevice, stream);
}

// Round 4
// 412.324 us; speedup vs baseline: 7.8690x; 1.2573x over previous
//
#include <hip/hip_runtime.h>

// GCNLinkPredictor: 2-layer GCN, N=100000, E=3.2M, F=128, U=1000.
// R4: atomic-free degree histogram (LDS-chunked, packed u16 counters, plain
// coalesced partial flush + reduce) replaces 3.2M device-scope atomics that
// were RMW-ing through the per-XCD L2s (100MB WRITE_SIZE, 129us). Scan chain
// fused: dual-scan (degF+fr) in 3 kernels, flist/nf folded into scan-final.

#define F_DIM 128
#define U_USERS 1000
#define SCAN_CHUNK 1024
#define NFCAP 48000     // frontier cap (expected ~33K)
#define NCHUNK 3        // node-space chunks for histogram
#define SBIN 40960      // nodes per chunk (3*40960 >= 100000)
#define SW (SBIN / 2)   // packed words per chunk (2 x u16 per word)
#define PSLICE 85       // edge slices per chunk -> 255 blocks

// ---- histogram: LDS packed counters, no global atomics ----
// block (c,p): chunk c = blockIdx%3, slice p = blockIdx/3. Also marks fr[src]
// for edges with dst < U (chunk-0 blocks only; ~32K idempotent stores).
__global__ __launch_bounds__(1024) void hist_kernel(const int* __restrict__ src,
                                                    const int* __restrict__ dst,
                                                    unsigned int* __restrict__ partial,
                                                    int* __restrict__ fr, int E, int n) {
    __shared__ unsigned int h[SW];   // 80 KB
    int tid = threadIdx.x;
    int c = blockIdx.x % NCHUNK;
    int p = blockIdx.x / NCHUNK;
    for (int i = tid; i < SW; i += 1024) h[i] = 0u;
    __syncthreads();

    int lo = c * SBIN;
    int hi = lo + SBIN;
    int len = (E + PSLICE - 1) / PSLICE;
    int base = p * len;
    int end = min(E, base + len);
    for (int e = base + tid; e < end; e += 1024) {
        int d = dst[e];
        if ((unsigned)d < (unsigned)n) {
            if (d >= lo && d < hi) {
                int local = d - lo;
                atomicAdd(&h[local >> 1], 1u << ((local & 1) << 4));  // LDS atomic
            }
            if (c == 0 && d < U_USERS) {
                int s = src[e];
                if ((unsigned)s < (unsigned)n) fr[s] = 1;
            }
        }
    }
    __syncthreads();
    unsigned int* outp = partial + ((size_t)(c * PSLICE + p)) * SW;
    for (int i = tid; i < SW; i += 1024) outp[i] = h[i];   // coalesced, no atomics
}

// ---- reduce partials -> deg; fused prep: inv, degF, fr[i<U]=1 ----
__global__ void reduce_prep_kernel(const unsigned int* __restrict__ partial,
                                   float* __restrict__ inv, int* __restrict__ fr,
                                   int* __restrict__ degF, int n) {
    int t = blockIdx.x * blockDim.x + threadIdx.x;   // global word index
    if (t >= NCHUNK * SW) return;
    int c = t / SW, w = t % SW;
    unsigned int a0 = 0, a1 = 0;
    const unsigned int* basep = partial + (size_t)c * PSLICE * SW + w;
#pragma unroll 5
    for (int p = 0; p < PSLICE; ++p) {
        unsigned int v = basep[(size_t)p * SW];
        a0 += v & 0xFFFFu;
        a1 += v >> 16;
    }
    int i0 = c * SBIN + 2 * w;
#pragma unroll
    for (int k = 0; k < 2; ++k) {
        int i = i0 + k;
        unsigned int dg = k ? a1 : a0;
        if (i < n) {
            inv[i] = rsqrtf((float)dg + 1.0f);
            bool isfr = (i < U_USERS) || (fr[i] != 0);
            if (i < U_USERS) fr[i] = 1;
            degF[i] = isfr ? (int)dg : 0;
        }
    }
}

// ---- dual exclusive scan (degF -> rp, fr -> remap), 3 kernels ----
__global__ void scan_reduce2_kernel(const int* __restrict__ dA, const int* __restrict__ dB,
                                    int* __restrict__ pA, int* __restrict__ pB, int n) {
    __shared__ int sdata[256];
    int b = blockIdx.x, t = threadIdx.x;
    int base = b * SCAN_CHUNK;
    int sumA = 0, sumB = 0;
#pragma unroll
    for (int i = 0; i < 4; ++i) {
        int idx = base + t + 256 * i;
        if (idx < n) { sumA += dA[idx]; sumB += dB[idx]; }
    }
    sdata[t] = sumA; __syncthreads();
    for (int s = 128; s > 0; s >>= 1) { if (t < s) sdata[t] += sdata[t + s]; __syncthreads(); }
    if (t == 0) pA[b] = sdata[0];
    __syncthreads();
    sdata[t] = sumB; __syncthreads();
    for (int s = 128; s > 0; s >>= 1) { if (t < s) sdata[t] += sdata[t + s]; __syncthreads(); }
    if (t == 0) pB[b] = sdata[0];
}

__global__ void scan_partials2_kernel(int* __restrict__ pA, int* __restrict__ pB, int nb) {
    int t = threadIdx.x;
    if (t == 0)  { int run = 0; for (int i = 0; i < nb; ++i) { int v = pA[i]; pA[i] = run; run += v; } }
    if (t == 64) { int run = 0; for (int i = 0; i < nb; ++i) { int v = pB[i]; pB[i] = run; run += v; } }
}

__global__ void scan_final2_kernel(const int* __restrict__ dA, const int* __restrict__ pA,
                                   int* __restrict__ rp,
                                   const int* __restrict__ dB, const int* __restrict__ pB,
                                   int* __restrict__ remap,
                                   int* __restrict__ flist, int* __restrict__ nf_dev, int n) {
    __shared__ int sthread[256];
    int b = blockIdx.x, t = threadIdx.x;
    int base = b * SCAN_CHUNK;
    {   // pass A: degF -> rp (exclusive)
        int v[4]; int sum = 0;
#pragma unroll
        for (int i = 0; i < 4; ++i) { int idx = base + 4 * t + i; v[i] = (idx < n) ? dA[idx] : 0; sum += v[i]; }
        sthread[t] = sum; __syncthreads();
        for (int ofs = 1; ofs < 256; ofs <<= 1) {
            int val = (t >= ofs) ? sthread[t - ofs] : 0;
            __syncthreads(); sthread[t] += val; __syncthreads();
        }
        int run = sthread[t] - sum + pA[b];
#pragma unroll
        for (int i = 0; i < 4; ++i) { int idx = base + 4 * t + i; if (idx < n) rp[idx] = run; run += v[i]; }
        __syncthreads();
    }
    {   // pass B: fr -> remap (exclusive) + flist + nf
        int v[4]; int sum = 0;
#pragma unroll
        for (int i = 0; i < 4; ++i) { int idx = base + 4 * t + i; v[i] = (idx < n) ? dB[idx] : 0; sum += v[i]; }
        sthread[t] = sum; __syncthreads();
        for (int ofs = 1; ofs < 256; ofs <<= 1) {
            int val = (t >= ofs) ? sthread[t - ofs] : 0;
            __syncthreads(); sthread[t] += val; __syncthreads();
        }
        int run = sthread[t] - sum + pB[b];
#pragma unroll
        for (int i = 0; i < 4; ++i) {
            int idx = base + 4 * t + i;
            if (idx < n) {
                remap[idx] = run;
                if (v[i] && run < NFCAP) flist[run] = idx;
                if (idx == n - 1) *nf_dev = min(run + v[i], NFCAP);
            }
            run += v[i];
        }
    }
}

// ---- CSR fill (frontier rows only); rp becomes shifted rowptr (bucket end) ----
__global__ void fill_csr_kernel(const int* __restrict__ src, const int* __restrict__ dst,
                                const int* __restrict__ fr,
                                int* __restrict__ rp, int* __restrict__ col, int E, int n) {
    int e = blockIdx.x * blockDim.x + threadIdx.x;
    if (e < E) {
        int d = dst[e], s = src[e];
        if ((unsigned)d < (unsigned)n && (unsigned)s < (unsigned)n && fr[d]) {
            int pos = atomicAdd(&rp[d], 1);
            if ((unsigned)pos < (unsigned)E) col[pos] = s;
        }
    }
}

// ---- dense GEMM: out[n,128] = X[n,128] @ W[128,128] ----
__global__ __launch_bounds__(256) void gemm_nn_kernel(const float* __restrict__ X,
                                                      const float* __restrict__ W,
                                                      float* __restrict__ out, int nrows) {
    __shared__ float Ws[F_DIM * F_DIM];
    __shared__ float Xs[F_DIM * 32];

    int tid = threadIdx.x;
    const float4* W4 = (const float4*)W;
    float4* Ws4 = (float4*)Ws;
#pragma unroll
    for (int i = 0; i < 16; ++i) Ws4[tid + 256 * i] = W4[tid + 256 * i];

    int rowBase = blockIdx.x * 32;
#pragma unroll
    for (int i = 0; i < 4; ++i) {
        int j = tid + 256 * i;
        int r = j >> 5;
        int k4 = j & 31;
        int row = rowBase + r;
        float4 v = make_float4(0.f, 0.f, 0.f, 0.f);
        if (row < nrows) v = ((const float4*)(X + (size_t)row * F_DIM))[k4];
        Xs[(4 * k4 + 0) * 32 + r] = v.x;
        Xs[(4 * k4 + 1) * 32 + r] = v.y;
        Xs[(4 * k4 + 2) * 32 + r] = v.z;
        Xs[(4 * k4 + 3) * 32 + r] = v.w;
    }
    __syncthreads();

    int c = tid & 31;
    int r0 = (tid >> 5) * 4;
    float4 acc0 = make_float4(0, 0, 0, 0);
    float4 acc1 = make_float4(0, 0, 0, 0);
    float4 acc2 = make_float4(0, 0, 0, 0);
    float4 acc3 = make_float4(0, 0, 0, 0);

    for (int k = 0; k < F_DIM; ++k) {
        float4 wv = *(const float4*)(Ws + k * F_DIM + 4 * c);
        float x0 = Xs[k * 32 + r0 + 0];
        float x1 = Xs[k * 32 + r0 + 1];
        float x2 = Xs[k * 32 + r0 + 2];
        float x3 = Xs[k * 32 + r0 + 3];
        acc0.x += x0 * wv.x; acc0.y += x0 * wv.y; acc0.z += x0 * wv.z; acc0.w += x0 * wv.w;
        acc1.x += x1 * wv.x; acc1.y += x1 * wv.y; acc1.z += x1 * wv.z; acc1.w += x1 * wv.w;
        acc2.x += x2 * wv.x; acc2.y += x2 * wv.y; acc2.z += x2 * wv.z; acc2.w += x2 * wv.w;
        acc3.x += x3 * wv.x; acc3.y += x3 * wv.y; acc3.z += x3 * wv.z; acc3.w += x3 * wv.w;
    }

    float4 accs[4] = {acc0, acc1, acc2, acc3};
#pragma unroll
    for (int i = 0; i < 4; ++i) {
        int row = rowBase + r0 + i;
        if (row < nrows)
            ((float4*)(out + (size_t)row * F_DIM))[c] = accs[i];
    }
}

// ---- GEMM with device-side row count (compact frontier rows) ----
__global__ __launch_bounds__(256) void gemm_nn_dyn_kernel(const float* __restrict__ X,
                                                          const float* __restrict__ W,
                                                          float* __restrict__ out,
                                                          const int* __restrict__ nrows_p) {
    int nrows = *nrows_p;
    int rowBase = blockIdx.x * 32;
    if (rowBase >= nrows) return;

    __shared__ float Ws[F_DIM * F_DIM];
    __shared__ float Xs[F_DIM * 32];

    int tid = threadIdx.x;
    const float4* W4 = (const float4*)W;
    float4* Ws4 = (float4*)Ws;
#pragma unroll
    for (int i = 0; i < 16; ++i) Ws4[tid + 256 * i] = W4[tid + 256 * i];

#pragma unroll
    for (int i = 0; i < 4; ++i) {
        int j = tid + 256 * i;
        int r = j >> 5;
        int k4 = j & 31;
        int row = rowBase + r;
        float4 v = make_float4(0.f, 0.f, 0.f, 0.f);
        if (row < nrows) v = ((const float4*)(X + (size_t)row * F_DIM))[k4];
        Xs[(4 * k4 + 0) * 32 + r] = v.x;
        Xs[(4 * k4 + 1) * 32 + r] = v.y;
        Xs[(4 * k4 + 2) * 32 + r] = v.z;
        Xs[(4 * k4 + 3) * 32 + r] = v.w;
    }
    __syncthreads();

    int c = tid & 31;
    int r0 = (tid >> 5) * 4;
    float4 acc0 = make_float4(0, 0, 0, 0);
    float4 acc1 = make_float4(0, 0, 0, 0);
    float4 acc2 = make_float4(0, 0, 0, 0);
    float4 acc3 = make_float4(0, 0, 0, 0);

    for (int k = 0; k < F_DIM; ++k) {
        float4 wv = *(const float4*)(Ws + k * F_DIM + 4 * c);
        float x0 = Xs[k * 32 + r0 + 0];
        float x1 = Xs[k * 32 + r0 + 1];
        float x2 = Xs[k * 32 + r0 + 2];
        float x3 = Xs[k * 32 + r0 + 3];
        acc0.x += x0 * wv.x; acc0.y += x0 * wv.y; acc0.z += x0 * wv.z; acc0.w += x0 * wv.w;
        acc1.x += x1 * wv.x; acc1.y += x1 * wv.y; acc1.z += x1 * wv.z; acc1.w += x1 * wv.w;
        acc2.x += x2 * wv.x; acc2.y += x2 * wv.y; acc2.z += x2 * wv.z; acc2.w += x2 * wv.w;
        acc3.x += x3 * wv.x; acc3.y += x3 * wv.y; acc3.z += x3 * wv.z; acc3.w += x3 * wv.w;
    }

    float4 accs[4] = {acc0, acc1, acc2, acc3};
#pragma unroll
    for (int i = 0; i < 4; ++i) {
        int row = rowBase + r0 + i;
        if (row < nrows)
            ((float4*)(out + (size_t)row * F_DIM))[c] = accs[i];
    }
}

// ---- layer-1 gather over compact frontier rows ----
__global__ __launch_bounds__(256) void gather_l1_kernel(const float* __restrict__ xw,
                                                        const float* __restrict__ inv,
                                                        const int* __restrict__ rp,
                                                        const int* __restrict__ col,
                                                        const int* __restrict__ flist,
                                                        const int* __restrict__ nf_p,
                                                        const float* __restrict__ b,
                                                        float* __restrict__ h1c) {
    int ci = blockIdx.x * 4 + (threadIdx.x >> 6);
    if (ci >= *nf_p) return;
    int lane = threadIdx.x & 63;
    int node = flist[ci];
    int start = (node == 0) ? 0 : rp[node - 1];
    int end = rp[node];

    float accx = 0.f, accy = 0.f;
    for (int base = start; base < end; base += 64) {
        int j = base + lane;
        int s_l = 0; float c_l = 0.f;
        if (j < end) { s_l = col[j]; c_l = inv[s_l]; }
        int cnt = min(64, end - base);
        int i = 0;
        for (; i + 4 <= cnt; i += 4) {
            int s0 = __shfl(s_l, i + 0); float f0 = __shfl(c_l, i + 0);
            int s1 = __shfl(s_l, i + 1); float f1 = __shfl(c_l, i + 1);
            int s2 = __shfl(s_l, i + 2); float f2 = __shfl(c_l, i + 2);
            int s3 = __shfl(s_l, i + 3); float f3 = __shfl(c_l, i + 3);
            float2 v0 = ((const float2*)(xw + (size_t)s0 * F_DIM))[lane];
            float2 v1 = ((const float2*)(xw + (size_t)s1 * F_DIM))[lane];
            float2 v2 = ((const float2*)(xw + (size_t)s2 * F_DIM))[lane];
            float2 v3 = ((const float2*)(xw + (size_t)s3 * F_DIM))[lane];
            accx += v0.x * f0 + v1.x * f1 + v2.x * f2 + v3.x * f3;
            accy += v0.y * f0 + v1.y * f1 + v2.y * f2 + v3.y * f3;
        }
        for (; i < cnt; ++i) {
            int s0 = __shfl(s_l, i); float f0 = __shfl(c_l, i);
            float2 v0 = ((const float2*)(xw + (size_t)s0 * F_DIM))[lane];
            accx += v0.x * f0;
            accy += v0.y * f0;
        }
    }

    float ivd = inv[node];
    float2 self = ((const float2*)(xw + (size_t)node * F_DIM))[lane];
    float vx = accx * ivd + self.x * ivd * ivd + b[lane * 2];
    float vy = accy * ivd + self.y * ivd * ivd + b[lane * 2 + 1];
    vx = vx > 0.f ? vx : expf(vx) - 1.f;
    vy = vy > 0.f ? vy : expf(vy) - 1.f;
    ((float2*)(h1c + (size_t)ci * F_DIM))[lane] = make_float2(vx, vy);
}

// ---- layer-2 gather over rows [0,U): cols remapped into compact xwc ----
__global__ __launch_bounds__(256) void gather_l2_kernel(const float* __restrict__ xwc,
                                                        const float* __restrict__ inv,
                                                        const int* __restrict__ rp,
                                                        const int* __restrict__ col,
                                                        const int* __restrict__ remap,
                                                        const float* __restrict__ b,
                                                        float* __restrict__ out) {
    int node = blockIdx.x * 4 + (threadIdx.x >> 6);
    if (node >= U_USERS) return;
    int lane = threadIdx.x & 63;
    int start = (node == 0) ? 0 : rp[node - 1];
    int end = rp[node];

    float accx = 0.f, accy = 0.f;
    for (int base = start; base < end; base += 64) {
        int j = base + lane;
        int r_l = 0; float c_l = 0.f;
        if (j < end) { int s = col[j]; c_l = inv[s]; r_l = remap[s]; }
        int cnt = min(64, end - base);
        for (int i = 0; i < cnt; ++i) {
            int r0 = __shfl(r_l, i); float f0 = __shfl(c_l, i);
            float2 v0 = ((const float2*)(xwc + (size_t)r0 * F_DIM))[lane];
            accx += v0.x * f0;
            accy += v0.y * f0;
        }
    }

    float ivd = inv[node];
    float2 self = ((const float2*)(xwc + (size_t)node * F_DIM))[lane];  // remap[node]==node for node<U
    float vx = accx * ivd + self.x * ivd * ivd + b[lane * 2];
    float vy = accy * ivd + self.y * ivd * ivd + b[lane * 2 + 1];
    vx = vx > 0.f ? vx : expf(vx) - 1.f;
    vy = vy > 0.f ? vy : expf(vy) - 1.f;
    ((float2*)(out + (size_t)node * F_DIM))[lane] = make_float2(vx, vy);
}

extern "C" void kernel_launch(void* const* d_in, const int* in_sizes, int n_in,
                              void* d_out, int out_size, void* d_ws, size_t ws_size,
                              hipStream_t stream) {
    const float* x  = (const float*)d_in[0];
    const int*   ei = (const int*)d_in[1];   // [2, E] int32
    const float* W1 = (const float*)d_in[2];
    const float* b1 = (const float*)d_in[3];
    const float* W2 = (const float*)d_in[4];
    const float* b2 = (const float*)d_in[5];
    float* out = (float*)d_out;

    int n = in_sizes[0] / F_DIM;   // 100000
    int E = in_sizes[1] / 2;       // 3200000
    const int* srcI = ei;
    const int* dstI = ei + E;

    // workspace layout (~112 MB)
    float* xw    = (float*)d_ws;                     // n*128 f (xw1; reused as xwc)
    float* h1c   = xw + (size_t)n * F_DIM;           // NFCAP*128 f
    float* inv   = h1c + (size_t)NFCAP * F_DIM;      // n f
    int* fr      = (int*)(inv + n);                  // n
    int* degF    = fr + n;                           // n
    int* remap   = degF + n;                         // n
    int* rp      = remap + n;                        // n
    int* flist   = rp + n;                           // NFCAP
    int* pA      = flist + NFCAP;                    // 1024
    int* pB      = pA + 1024;                        // 1024
    int* nf_dev  = pB + 1024;                        // 1 (+pad)
    int* col     = nf_dev + 16;                      // E
    unsigned int* partialH = (unsigned int*)(col + E);  // NCHUNK*PSLICE*SW = 20.9 MB

    int nb = (n + SCAN_CHUNK - 1) / SCAN_CHUNK;      // 98

    hipMemsetAsync(fr, 0, (size_t)n * sizeof(int), stream);

    // histogram (atomic-free) + frontier mark
    hist_kernel<<<NCHUNK * PSLICE, 1024, 0, stream>>>(srcI, dstI, partialH, fr, E, n);
    reduce_prep_kernel<<<(NCHUNK * SW + 255) / 256, 256, 0, stream>>>(partialH, inv, fr, degF, n);

    // dual scan: degF -> rp, fr -> remap (+ flist, nf)
    scan_reduce2_kernel<<<nb, 256, 0, stream>>>(degF, fr, pA, pB, n);
    scan_partials2_kernel<<<1, 128, 0, stream>>>(pA, pB, nb);
    scan_final2_kernel<<<nb, 256, 0, stream>>>(degF, pA, rp, fr, pB, remap, flist, nf_dev, n);

    fill_csr_kernel<<<(E + 255) / 256, 256, 0, stream>>>(srcI, dstI, fr, rp, col, E, n);

    // layer 1: full GEMM, frontier-only gather
    gemm_nn_kernel<<<(n + 31) / 32, 256, 0, stream>>>(x, W1, xw, n);
    gather_l1_kernel<<<(NFCAP + 3) / 4, 256, 0, stream>>>(xw, inv, rp, col, flist, nf_dev, b1, h1c);

    // layer 2: compact GEMM (nf rows), gather over U rows
    gemm_nn_dyn_kernel<<<(NFCAP + 31) / 32, 256, 0, stream>>>(h1c, W2, xw, nf_dev);
    gather_l2_kernel<<<(U_USERS + 3) / 4, 256, 0, stream>>>(xw, inv, rp, col, remap, b2, out);

    // passthrough rows [U:]
    hipMemcpyAsync(out + (size_t)U_USERS * F_DIM, x + (size_t)U_USERS * F_DIM,
                   (size_t)(n - U_USERS) * F_DIM * sizeof(float),
                   hipMemcpyDeviceToDevice, stream);
}